// Round 6
// baseline (218.526 us; speedup 1.0000x reference)
//
#include <hip/hip_runtime.h>

typedef float f32x4 __attribute__((ext_vector_type(4)));

// 16-segment breakpoints (module constants from the reference)
__device__ __constant__ float c_seg[16] = {
    0.0001f, 0.002f, 0.004f, 0.007f, 0.01f, 0.03f, 0.1f, 0.2f,
    0.3f,    1.0f,   2.0f,   4.0f,   8.0f,  16.0f, 64.0f, 1024.0f};

__device__ __forceinline__ float eval_seg(float x,
                                          const float* __restrict__ s_seg,
                                          const float* __restrict__ s_y0,
                                          const float* __restrict__ s_k) {
    // clamp into table range
    float xc = fminf(fmaxf(x, 0.0001f), 1024.0f);
    // searchsorted(side='left') - 1, clamped to [0,14]:
    // idx = count of seg[j] < xc over j=1..14
    int idx = 0;
    idx += (xc > 0.002f);
    idx += (xc > 0.004f);
    idx += (xc > 0.007f);
    idx += (xc > 0.01f);
    idx += (xc > 0.03f);
    idx += (xc > 0.1f);
    idx += (xc > 0.2f);
    idx += (xc > 0.3f);
    idx += (xc > 1.0f);
    idx += (xc > 2.0f);
    idx += (xc > 4.0f);
    idx += (xc > 8.0f);
    idx += (xc > 16.0f);
    idx += (xc > 64.0f);
    // 16 words sit in 16 distinct LDS banks -> per-lane gather is conflict-free
    // (counter-verified: SQ_LDS_BANK_CONFLICT == 0)
    float x0 = s_seg[idx];
    float y0 = s_y0[idx];
    float k  = s_k[idx];
    return fmaf(xc - x0, k, y0);
}

// Simple grid-stride loop: R2 (x4) and R5 (x2) unrolls both regressed ~7%;
// the compiler schedules this form best. Do not re-unroll.
__global__ __launch_bounds__(256) void invsqrt16_kernel(
        const f32x4* __restrict__ x, f32x4* __restrict__ out, int n4) {
    __shared__ float s_seg[16];
    __shared__ float s_y0[16];
    __shared__ float s_k[16];
    if (threadIdx.x < 16) {
        int j = threadIdx.x;
        float s0 = c_seg[j];
        float s1 = c_seg[(j < 15) ? j + 1 : 15];
        float y0 = 1.0f / sqrtf(s0);
        float y1 = 1.0f / sqrtf(s1);
        s_seg[j] = s0;
        s_y0[j]  = y0;
        s_k[j]   = (j < 15) ? (y1 - y0) / (s1 - s0) : 0.0f;
    }
    __syncthreads();

    int stride = gridDim.x * blockDim.x;
    for (int i = blockIdx.x * blockDim.x + threadIdx.x; i < n4; i += stride) {
        // nt LOAD: streaming read, don't evict L2 write-combining lines.
        f32x4 v = __builtin_nontemporal_load(&x[i]);
        f32x4 r;
        r.x = eval_seg(v.x, s_seg, s_y0, s_k);
        r.y = eval_seg(v.y, s_seg, s_y0, s_k);
        r.z = eval_seg(v.z, s_seg, s_y0, s_k);
        r.w = eval_seg(v.w, s_seg, s_y0, s_k);
        // NORMAL store: let L2 absorb/combine write lines (fill kernel's
        // 6.7 TB/s uses normal stores) — A/B vs R4's nt store.
        out[i] = r;
    }
}

extern "C" void kernel_launch(void* const* d_in, const int* in_sizes, int n_in,
                              void* d_out, int out_size, void* d_ws, size_t ws_size,
                              hipStream_t stream) {
    const float* x = (const float*)d_in[0];
    float* out = (float*)d_out;
    long long n = in_sizes[0];

    long long n4 = n >> 2;            // n = 32*4096*1024, divisible by 4
    int threads = 256;
    long long want = (n4 + threads - 1) / threads;
    int blocks = (int)((want < 2048) ? (want > 0 ? want : 1) : 2048);

    invsqrt16_kernel<<<blocks, threads, 0, stream>>>(
        (const f32x4*)x, (f32x4*)out, (int)n4);

    (void)d_ws; (void)ws_size; (void)n_in; (void)out_size;
}

// Round 7
// 212.387 us; speedup vs baseline: 1.0289x; 1.0289x over previous
//
#include <hip/hip_runtime.h>

typedef float f32x4 __attribute__((ext_vector_type(4)));

// Piecewise-linear 1/sqrt: y = k[i]*xc + b[i] on segment i, where
// k[i] = (lut[i+1]-lut[i])/(seg[i+1]-seg[i]), b[i] = lut[i] - seg[i]*k[i].
// All constants precomputed in double, verified exact at every breakpoint:
//   y(seg[i]) = lut[i], y(seg[i+1]) = lut[i+1] for all i.
// Selection: searchsorted-left(-1) == "last segment whose left edge is < xc",
// i.e. strict-> cascade. No LDS, no DS pipe: pure cndmask cascade on
// SGPR-hoisted constants.
__device__ __forceinline__ float eval_seg(float x) {
    float xc = fminf(fmaxf(x, 1e-4f), 1024.0f);
    float k = -40862.8001184221f;  // segment [1e-4, 0.002)
    float b = 104.086280011842f;
#define SEL(t, kk, bb) { bool c = xc > (t); k = c ? (kk) : k; b = c ? (bb) : b; }
    SEL(0.002f, -3274.645737078f,    28.9099712491540f)   // [0.002,0.004)
    SEL(0.004f, -1286.36740249933f,  20.9568579108390f)   // [0.004,0.007)
    SEL(0.007f, -650.762031114633f,  16.5076203111463f)   // [0.007,0.01)
    SEL(0.01f,  -211.324865405185f,  12.1132486540519f)   // [0.01,0.03)
    SEL(0.03f,  -37.3032147389700f,  6.89259913406540f)   // [0.03,0.1)
    SEL(0.1f,   -9.26209682668600f,  4.08848734283700f)   // [0.1,0.2)
    SEL(0.2f,   -4.10326119149200f,  3.05672021579820f)   // [0.2,0.3)
    SEL(0.3f,   -1.17963122621510f,  2.17963122621510f)   // [0.3,1)
    SEL(1.0f,   -0.292893218813452f, 1.29289321881345f)   // [1,2)
    SEL(2.0f,   -0.103553390593274f, 0.914213562373095f)  // [2,4)
    SEL(4.0f,   -0.0366116523516816f,0.646446609406726f)  // [4,8)
    SEL(8.0f,   -0.0129441738241630f,0.457106781186548f)  // [8,16)
    SEL(16.0f,  -0.00260416666666667f,0.291666666666667f) // [16,64)
    SEL(64.0f,  -9.765625e-5f,       0.13125f)            // [64,1024]
#undef SEL
    return fmaf(xc, k, b);
}

// Simple grid-stride loop: R2 (x4) and R5 (x2) unrolls both regressed ~7%;
// the compiler schedules this form best. nt on BOTH load and store is the
// verified best cache config (R4=200us vs R1 plain=215, R6 nt-load-only=219).
__global__ __launch_bounds__(256) void invsqrt16_kernel(
        const f32x4* __restrict__ x, f32x4* __restrict__ out, int n4) {
    int stride = gridDim.x * blockDim.x;
    for (int i = blockIdx.x * blockDim.x + threadIdx.x; i < n4; i += stride) {
        f32x4 v = __builtin_nontemporal_load(&x[i]);
        f32x4 r;
        r.x = eval_seg(v.x);
        r.y = eval_seg(v.y);
        r.z = eval_seg(v.z);
        r.w = eval_seg(v.w);
        __builtin_nontemporal_store(r, &out[i]);
    }
}

extern "C" void kernel_launch(void* const* d_in, const int* in_sizes, int n_in,
                              void* d_out, int out_size, void* d_ws, size_t ws_size,
                              hipStream_t stream) {
    const float* x = (const float*)d_in[0];
    float* out = (float*)d_out;
    long long n = in_sizes[0];

    long long n4 = n >> 2;            // n = 32*4096*1024, divisible by 4
    int threads = 256;
    long long want = (n4 + threads - 1) / threads;
    int blocks = (int)((want < 2048) ? (want > 0 ? want : 1) : 2048);

    invsqrt16_kernel<<<blocks, threads, 0, stream>>>(
        (const f32x4*)x, (f32x4*)out, (int)n4);

    (void)d_ws; (void)ws_size; (void)n_in; (void)out_size;
}

// Round 8
// 194.136 us; speedup vs baseline: 1.1256x; 1.0940x over previous
//
#include <hip/hip_runtime.h>

typedef float f32x4 __attribute__((ext_vector_type(4)));

// 16-segment breakpoints (module constants from the reference)
__device__ __constant__ float c_seg[16] = {
    0.0001f, 0.002f, 0.004f, 0.007f, 0.01f, 0.03f, 0.1f, 0.2f,
    0.3f,    1.0f,   2.0f,   4.0f,   8.0f,  16.0f, 64.0f, 1024.0f};

__device__ __forceinline__ float eval_seg(float x,
                                          const float* __restrict__ s_seg,
                                          const float* __restrict__ s_y0,
                                          const float* __restrict__ s_k) {
    float xc = fminf(fmaxf(x, 0.0001f), 1024.0f);
    // searchsorted(side='left') - 1, clamped to [0,14]
    int idx = 0;
    idx += (xc > 0.002f);
    idx += (xc > 0.004f);
    idx += (xc > 0.007f);
    idx += (xc > 0.01f);
    idx += (xc > 0.03f);
    idx += (xc > 0.1f);
    idx += (xc > 0.2f);
    idx += (xc > 0.3f);
    idx += (xc > 1.0f);
    idx += (xc > 2.0f);
    idx += (xc > 4.0f);
    idx += (xc > 8.0f);
    idx += (xc > 16.0f);
    idx += (xc > 64.0f);
    // 16 words in 16 distinct banks -> conflict-free gather (R7 showed
    // replacing DS with cndmask-cascade VALU is net-worse: 212 vs 200 us)
    float x0 = s_seg[idx];
    float y0 = s_y0[idx];
    float k  = s_k[idx];
    return fmaf(xc - x0, k, y0);
}

__device__ __forceinline__ f32x4 eval4(f32x4 v,
                                       const float* __restrict__ s_seg,
                                       const float* __restrict__ s_y0,
                                       const float* __restrict__ s_k) {
    f32x4 r;
    r.x = eval_seg(v.x, s_seg, s_y0, s_k);
    r.y = eval_seg(v.y, s_seg, s_y0, s_k);
    r.z = eval_seg(v.z, s_seg, s_y0, s_k);
    r.w = eval_seg(v.w, s_seg, s_y0, s_k);
    return r;
}

// Wave-contiguous x4 unroll: lane handles base, +64, +128, +192 (f32x4 units)
// -> each wave owns a contiguous 4 KB window; the 3 extra loads/stores are
// imm-offset (1024/2048/3072 B), zero extra address math, DRAM locality kept.
// (R2/R5's grid-blocked unrolls put in-flight loads 8 MB apart — that, not
// MLP itself, is the suspected regression mechanism.)
// (256,8) pins <=64 VGPRs so the occupancy cliff cannot recur.
__global__ __launch_bounds__(256, 8) void invsqrt16_kernel(
        const f32x4* __restrict__ x, f32x4* __restrict__ out, int n4) {
    __shared__ float s_seg[16];
    __shared__ float s_y0[16];
    __shared__ float s_k[16];
    if (threadIdx.x < 16) {
        int j = threadIdx.x;
        float s0 = c_seg[j];
        float s1 = c_seg[(j < 15) ? j + 1 : 15];
        float y0 = 1.0f / sqrtf(s0);
        float y1 = 1.0f / sqrtf(s1);
        s_seg[j] = s0;
        s_y0[j]  = y0;
        s_k[j]   = (j < 15) ? (y1 - y0) / (s1 - s0) : 0.0f;
    }
    __syncthreads();

    const int lane = threadIdx.x & 63;
    const int wave = threadIdx.x >> 6;
    const int gstride = gridDim.x * 1024;           // f32x4 units per grid pass
    int i = blockIdx.x * 1024 + wave * 256 + lane;  // wave owns 256 f32x4 = 4 KB

    for (; i + 192 < n4; i += gstride) {
        f32x4 v0 = __builtin_nontemporal_load(&x[i]);
        f32x4 v1 = __builtin_nontemporal_load(&x[i + 64]);
        f32x4 v2 = __builtin_nontemporal_load(&x[i + 128]);
        f32x4 v3 = __builtin_nontemporal_load(&x[i + 192]);
        f32x4 r0 = eval4(v0, s_seg, s_y0, s_k);
        f32x4 r1 = eval4(v1, s_seg, s_y0, s_k);
        f32x4 r2 = eval4(v2, s_seg, s_y0, s_k);
        f32x4 r3 = eval4(v3, s_seg, s_y0, s_k);
        __builtin_nontemporal_store(r0, &out[i]);
        __builtin_nontemporal_store(r1, &out[i + 64]);
        __builtin_nontemporal_store(r2, &out[i + 128]);
        __builtin_nontemporal_store(r3, &out[i + 192]);
    }
    // tail (n4 % (grid*1024) != 0 case; exact fit for this problem size)
    if (i < n4) {
#pragma unroll
        for (int o = 0; o < 256; o += 64) {
            if (i + o < n4) {
                f32x4 v = __builtin_nontemporal_load(&x[i + o]);
                __builtin_nontemporal_store(eval4(v, s_seg, s_y0, s_k),
                                            &out[i + o]);
            }
        }
    }
}

extern "C" void kernel_launch(void* const* d_in, const int* in_sizes, int n_in,
                              void* d_out, int out_size, void* d_ws, size_t ws_size,
                              hipStream_t stream) {
    const float* x = (const float*)d_in[0];
    float* out = (float*)d_out;
    long long n = in_sizes[0];

    long long n4 = n >> 2;            // n = 32*4096*1024, divisible by 4
    int threads = 256;
    long long chunks = (n4 + 1023) / 1024;          // 1024 f32x4 per block pass
    int blocks = (int)((chunks < 2048) ? (chunks > 0 ? chunks : 1) : 2048);

    invsqrt16_kernel<<<blocks, threads, 0, stream>>>(
        (const f32x4*)x, (f32x4*)out, (int)n4);

    (void)d_ws; (void)ws_size; (void)n_in; (void)out_size;
}